// Round 7
// baseline (307.774 us; speedup 1.0000x reference)
//
#include <hip/hip_runtime.h>
#include <hip/hip_bf16.h>
#include <math.h>

// Problem constants: N=100000, E=600000, D=128, H=4, F=32, L=3

__device__ __forceinline__ float leaky02(float x) {
    return x >= 0.f ? x : 0.2f * x;
}
__device__ __forceinline__ float leaky01(float x) {
    return x >= 0.f ? x : 0.01f * x;
}

// bf16 helpers (round-to-nearest-even)
__device__ __forceinline__ unsigned short f2bf(float f) {
    unsigned u = __float_as_uint(f);
    unsigned r = u + 0x7FFFu + ((u >> 16) & 1u);
    return (unsigned short)(r >> 16);
}
__device__ __forceinline__ float bf2f(unsigned short s) {
    return __uint_as_float(((unsigned)s) << 16);
}

typedef __attribute__((ext_vector_type(8))) short bf16x8;
typedef __attribute__((ext_vector_type(8))) unsigned short u16x8;
typedef __attribute__((ext_vector_type(4))) float f32x4;

// ---------------------------------------------------------------------------
// Sense-free software grid barrier. State lives in __device__ globals (NOT
// the re-poisoned workspace): count self-resets to 0 after each barrier,
// gen increases monotonically — safe across bench iterations and graph
// replays. Co-residency: the fused CSR kernel launches 98 blocks on a
// 256-CU chip with the stream idle -> all blocks resident immediately.
__device__ unsigned g_bar_count = 0;
__device__ unsigned g_bar_gen   = 0;

__device__ __forceinline__ void grid_barrier() {
    __syncthreads();
    if (threadIdx.x == 0) {
        __threadfence();   // make this block's stores device-visible
        unsigned gen = __hip_atomic_load(&g_bar_gen, __ATOMIC_RELAXED,
                                         __HIP_MEMORY_SCOPE_AGENT);
        unsigned arrived = __hip_atomic_fetch_add(&g_bar_count, 1u,
                                                  __ATOMIC_ACQ_REL,
                                                  __HIP_MEMORY_SCOPE_AGENT);
        if (arrived == gridDim.x - 1) {
            __hip_atomic_store(&g_bar_count, 0u, __ATOMIC_RELAXED,
                               __HIP_MEMORY_SCOPE_AGENT);
            __hip_atomic_fetch_add(&g_bar_gen, 1u, __ATOMIC_RELEASE,
                                   __HIP_MEMORY_SCOPE_AGENT);
        } else {
            while (__hip_atomic_load(&g_bar_gen, __ATOMIC_ACQUIRE,
                                     __HIP_MEMORY_SCOPE_AGENT) == gen)
                __builtin_amdgcn_s_sleep(1);
        }
        __threadfence();
    }
    __syncthreads();
}

// ---------------------------------------------------------------------------
// ONE-LAUNCH CSR build + all prep (replaces 6 kernels; removes 5 launch
// gaps and overlaps W-split/Mext/rank1 with the CSR phases).
// Phases: P0 init+prep | P1 atomic count | P2 tile sums | P3 block-0 scan
//         | P4 rowp + self-loop col | P5 edge scatter.
__global__ __launch_bounds__(1024) void csr_prep_kernel(
    int* __restrict__ deg, int N,
    const float* __restrict__ fc_W, const float* __restrict__ attn_l,
    const float* __restrict__ attn_r,
    short* __restrict__ Wh, short* __restrict__ Wl,
    short* __restrict__ Mh, short* __restrict__ Ml,
    const float* __restrict__ lW, const float* __restrict__ lb,
    const float* __restrict__ cb2, const float* __restrict__ pW,
    const float* __restrict__ pb,
    float* __restrict__ c1, float* __restrict__ c2, float* __restrict__ prm,
    const int* __restrict__ src, const int* __restrict__ dst,
    int* __restrict__ slot, int E,
    int* __restrict__ bsum, int* __restrict__ bpre,
    int* __restrict__ rowp, int* __restrict__ col)
{
    __shared__ int   sh_i[1024];
    __shared__ float sh_f[5 * 128];

    const int b = blockIdx.x;
    const int t = threadIdx.x;
    const int stride = gridDim.x * 1024;

    // ---- P0: deg init + W split (grid-stride); block 1: Mext; block 0: rank1
    for (int i = b * 1024 + t; i < N; i += stride) deg[i] = 1;
    for (int i = b * 1024 + t; i < 2 * 16384; i += stride) {
        const float* W = fc_W + 16384;   // layers 1,2
        int l    = i >> 14;
        int p    = i & 16383;
        int j    = p & 7;
        int lane = (p >> 3) & 63;
        int c    = (p >> 9) & 7;
        int kk   = p >> 12;
        int mr   = lane & 15;
        int quad = lane >> 4;
        int row  = c * 16 + mr;
        int d    = kk * 32 + quad * 8 + j;
        float f = W[(size_t)l * 16384 + row * 128 + d];
        unsigned short hi = f2bf(f);
        Wh[i] = (short)hi;
        Wl[i] = (short)f2bf(f - bf2f(hi));
    }
    if (b == 1) {
        // Mext rows for layers 1,2: one thread per (r,d), loop over l
        int r = t >> 7;                       // 0..7
        int d = t & 127;
        int hh = r & 3;
#pragma unroll
        for (int l = 0; l < 2; ++l) {
            const float* W  = fc_W + (size_t)(l + 1) * 16384;
            const float* al = attn_l + (l + 1) * 128;
            const float* ar = attn_r + (l + 1) * 128;
            short* mh = Mh + (size_t)l * 16 * 128;
            short* ml = Ml + (size_t)l * 16 * 128;
            const float* av = (r < 4) ? al : ar;
            float s = 0.f;
#pragma unroll
            for (int f = 0; f < 32; ++f)
                s += W[(size_t)(hh * 32 + f) * 128 + d] * av[hh * 32 + f];
            unsigned short hi = f2bf(s);
            mh[r * 128 + d] = (short)hi;
            ml[r * 128 + d] = (short)f2bf(s - bf2f(hi));
            mh[(r + 8) * 128 + d] = 0;        // zero rows 8..15
            ml[(r + 8) * 128 + d] = 0;
        }
    }
    if (b == 0) {
        // rank1 job: 8 lanes per output j, 16-deep dot + shfl reduce
        const float* W0 = fc_W;
        const float* al = attn_l;
        const float* ar = attn_r;
        int j = t >> 3, sub = t & 7;
        float s1 = 0.f, s2 = 0.f;
        int d0 = sub * 16;
#pragma unroll
        for (int k = 0; k < 16; ++k) {
            float wv = W0[j * 128 + d0 + k];
            s1 += lW[d0 + k] * wv;
            s2 += lb[d0 + k] * wv;
        }
#pragma unroll
        for (int m = 1; m <= 4; m <<= 1) {
            s1 += __shfl_xor(s1, m, 64);
            s2 += __shfl_xor(s2, m, 64);
        }
        if (sub == 0) {
            c1[j] = s1; c2[j] = s2;
            sh_f[j]       = s1 * al[j]; sh_f[128 + j] = s2 * al[j];
            sh_f[256 + j] = s1 * ar[j]; sh_f[384 + j] = s2 * ar[j];
            sh_f[512 + j] = cb2[j] * pW[j];
        }
        __syncthreads();
        if (t < 4) {
            float p = 0.f, q = 0.f, r = 0.f, s = 0.f;
            for (int f = 0; f < 32; ++f) {
                p += sh_f[t * 32 + f];       q += sh_f[128 + t * 32 + f];
                r += sh_f[256 + t * 32 + f]; s += sh_f[384 + t * 32 + f];
            }
            prm[t] = p; prm[4 + t] = q; prm[8 + t] = r; prm[12 + t] = s;
        }
        if (t == 0) {
            float cs = 0.f;
            for (int k = 0; k < 128; ++k) cs += sh_f[512 + k];
            prm[16] = cs + pb[0];
        }
    }
    grid_barrier();

    // ---- P1: per-dst edge count; slot = old count (>=1: self loop slot 0)
    for (int e = b * 1024 + t; e < E; e += stride)
        slot[e] = atomicAdd(&deg[dst[e]], 1);
    grid_barrier();

    // ---- P2: per-tile (1024) degree sums
    {
        int i = b * 1024 + t;
        int val = (i < N) ? deg[i] : 0;
#pragma unroll
        for (int m = 32; m >= 1; m >>= 1) val += __shfl_xor(val, m, 64);
        if ((t & 63) == 0) sh_i[t >> 6] = val;
        __syncthreads();
        if (t == 0) {
            int s = 0;
#pragma unroll
            for (int k = 0; k < 16; ++k) s += sh_i[k];
            bsum[b] = s;
        }
    }
    grid_barrier();

    // ---- P3: block 0 scans the <=128 tile sums
    if (b == 0) {
        int vbs = (t < 128 && t < (int)gridDim.x) ? bsum[t] : 0;
        if (t < 128) sh_i[t] = vbs;
        __syncthreads();
        for (int off = 1; off < 128; off <<= 1) {
            int u = (t >= off && t < 128) ? sh_i[t - off] : 0;
            __syncthreads();
            if (t < 128) sh_i[t] += u;
            __syncthreads();
        }
        if (t < (int)gridDim.x) bpre[t] = sh_i[t] - vbs;   // exclusive
        if (t == 0) rowp[N] = sh_i[127];                   // total
    }
    grid_barrier();

    // ---- P4: tile-local scan -> rowp; write self-loop col (slot 0)
    {
        int i = b * 1024 + t;
        int v = (i < N) ? deg[i] : 0;
        sh_i[t] = v;
        __syncthreads();
        for (int off = 1; off < 1024; off <<= 1) {
            int u = (t >= off) ? sh_i[t - off] : 0;
            __syncthreads();
            sh_i[t] += u;
            __syncthreads();
        }
        int pre = bpre[b] + sh_i[t] - v;
        if (i < N) {
            rowp[i] = pre;
            col[pre] = i;   // self loop at slot 0
        }
    }
    grid_barrier();

    // ---- P5: atomic-free edge scatter
    for (int e = b * 1024 + t; e < E; e += stride)
        col[rowp[dst[e]] + slot[e]] = src[e];
}

// ---------------------------------------------------------------------------
// LAYER-0 aggregation via rank-1 identity — edge-parallel across the 4
// lanes of each (vertex,head) group.
__global__ __launch_bounds__(256) void agg0_kernel(
    const float* __restrict__ w, const float* __restrict__ c1,
    const float* __restrict__ c2, const float* __restrict__ prm,
    const int* __restrict__ rowp, const int* __restrict__ col,
    const float* __restrict__ bias, unsigned short* __restrict__ xout, int N)
{
    const int lane = threadIdx.x & 63;
    const int q    = lane >> 4;
    const int l16  = lane & 15;
    const int v    = blockIdx.x * 16 + (threadIdx.x >> 6) * 4 + q;
    if (v >= N) return;

    const int r0 = rowp[v], r1 = rowp[v + 1];
    const int head = l16 >> 2;
    const int e4   = l16 & 3;        // edge slot within head group
    const int f0   = l16 * 8;
    const float pl = prm[head],     ql = prm[4 + head];
    const float pr = prm[8 + head], qr = prm[12 + head];

    const float wv  = w[v];
    const float erq = wv * pr + qr;
    const float mref = leaky02(wv * pl + ql + erq);   // self-loop e

    float S = 0.f, Sw = 0.f;
    for (int j = r0 + e4; j < r1; j += 4) {
        int u = col[j];                                // (j==r0 -> u==v)
        float wu = w[u];
        float e = leaky02(wu * pl + ql + erq);
        float d = fminf(e - mref, 80.f);
        float p = __expf(d);
        S += p; Sw += p * wu;
    }
    // quad-reduce (lanes of a head group are 4 consecutive lanes)
    S  += __shfl_xor(S, 1, 64);  S  += __shfl_xor(S, 2, 64);
    Sw += __shfl_xor(Sw, 1, 64); Sw += __shfl_xor(Sw, 2, 64);
    const float t = Sw / S;

    float4 a0 = *reinterpret_cast<const float4*>(&c1[f0]);
    float4 a1 = *reinterpret_cast<const float4*>(&c1[f0 + 4]);
    float4 g0 = *reinterpret_cast<const float4*>(&c2[f0]);
    float4 g1 = *reinterpret_cast<const float4*>(&c2[f0 + 4]);
    float4 b0 = *reinterpret_cast<const float4*>(&bias[f0]);
    float4 b1 = *reinterpret_cast<const float4*>(&bias[f0 + 4]);
    const float aa[8] = {a0.x, a0.y, a0.z, a0.w, a1.x, a1.y, a1.z, a1.w};
    const float gg[8] = {g0.x, g0.y, g0.z, g0.w, g1.x, g1.y, g1.z, g1.w};
    const float bb[8] = {b0.x, b0.y, b0.z, b0.w, b1.x, b1.y, b1.z, b1.w};

    u16x8 o;
#pragma unroll
    for (int k = 0; k < 8; ++k)
        o[k] = f2bf(leaky01(t * aa[k] + gg[k] + bb[k]));
    *reinterpret_cast<u16x8*>(&xout[(size_t)v * 128 + f0]) = o;
}

// ---------------------------------------------------------------------------
// MFMA bf16 GEMM (layers 1,2) + fused el/er tile — 32 rows/wave,
// FRAGMENT-PACKED W. mode 0 (layer1): write hb + el + er.
// mode 1 (layer2): skip hb; write yel[row*8+h*2] = {y_h = h.pW_h, el_h} + er.
__global__ __launch_bounds__(256) void gemm_mfma_kernel(
    const unsigned short* __restrict__ xb, const short* __restrict__ Wh,
    const short* __restrict__ Wl, const short* __restrict__ Mh,
    const short* __restrict__ Ml, unsigned short* __restrict__ hb,
    float* __restrict__ el, float* __restrict__ er,
    const float* __restrict__ pW, float* __restrict__ yel,
    int N, int mode)
{
    const int lane = threadIdx.x & 63;
    const int wv   = threadIdx.x >> 6;
    const int m0   = blockIdx.x * 128 + wv * 32;  // 32 rows per wave
    const int mr   = lane & 15;
    const int quad = lane >> 4;

    int r0 = m0 + mr;      if (r0 > N - 1) r0 = N - 1;   // clamped load rows
    int r1 = m0 + 16 + mr; if (r1 > N - 1) r1 = N - 1;
    const unsigned short* xp0 = xb + (size_t)r0 * 128 + quad * 8;
    const unsigned short* xp1 = xb + (size_t)r1 * 128 + quad * 8;

    f32x4 acc0[8], acc1[8], acce0, acce1;
#pragma unroll
    for (int c = 0; c < 8; ++c) {
        acc0[c] = (f32x4){0.f, 0.f, 0.f, 0.f};
        acc1[c] = (f32x4){0.f, 0.f, 0.f, 0.f};
    }
    acce0 = (f32x4){0.f, 0.f, 0.f, 0.f};
    acce1 = (f32x4){0.f, 0.f, 0.f, 0.f};

#pragma unroll
    for (int kk = 0; kk < 4; ++kk) {
        bf16x8 a0 = *reinterpret_cast<const bf16x8*>(xp0 + kk * 32);
        bf16x8 a1 = *reinterpret_cast<const bf16x8*>(xp1 + kk * 32);

        const int kb = kk * 32 + quad * 8;
        bf16x8 bh[8], bl[8];
#pragma unroll
        for (int c = 0; c < 8; ++c) {
            const size_t wo = (size_t)((kk * 8 + c) * 64 + lane) * 8;
            bh[c] = *reinterpret_cast<const bf16x8*>(Wh + wo);
            bl[c] = *reinterpret_cast<const bf16x8*>(Wl + wo);
        }
        bf16x8 eh = *reinterpret_cast<const bf16x8*>(Mh + (size_t)mr * 128 + kb);
        bf16x8 eo = *reinterpret_cast<const bf16x8*>(Ml + (size_t)mr * 128 + kb);
#pragma unroll
        for (int c = 0; c < 8; ++c) {
            acc0[c] = __builtin_amdgcn_mfma_f32_16x16x32_bf16(a0, bh[c], acc0[c], 0, 0, 0);
            acc0[c] = __builtin_amdgcn_mfma_f32_16x16x32_bf16(a0, bl[c], acc0[c], 0, 0, 0);
            acc1[c] = __builtin_amdgcn_mfma_f32_16x16x32_bf16(a1, bh[c], acc1[c], 0, 0, 0);
            acc1[c] = __builtin_amdgcn_mfma_f32_16x16x32_bf16(a1, bl[c], acc1[c], 0, 0, 0);
        }
        acce0 = __builtin_amdgcn_mfma_f32_16x16x32_bf16(a0, eh, acce0, 0, 0, 0);
        acce0 = __builtin_amdgcn_mfma_f32_16x16x32_bf16(a0, eo, acce0, 0, 0, 0);
        acce1 = __builtin_amdgcn_mfma_f32_16x16x32_bf16(a1, eh, acce1, 0, 0, 0);
        acce1 = __builtin_amdgcn_mfma_f32_16x16x32_bf16(a1, eo, acce1, 0, 0, 0);
    }

    if (mode == 0) {
#pragma unroll
        for (int i = 0; i < 4; ++i) {
            int rowA = m0 + quad * 4 + i;
            if (rowA < N) {
                unsigned short* hp = hb + (size_t)rowA * 128 + mr;
#pragma unroll
                for (int c = 0; c < 8; ++c) hp[c * 16] = f2bf(acc0[c][i]);
                if (mr < 4)       el[(size_t)rowA * 4 + mr]       = acce0[i];
                else if (mr < 8)  er[(size_t)rowA * 4 + (mr - 4)] = acce0[i];
            }
            int rowB = m0 + 16 + quad * 4 + i;
            if (rowB < N) {
                unsigned short* hp = hb + (size_t)rowB * 128 + mr;
#pragma unroll
                for (int c = 0; c < 8; ++c) hp[c * 16] = f2bf(acc1[c][i]);
                if (mr < 4)       el[(size_t)rowB * 4 + mr]       = acce1[i];
                else if (mr < 8)  er[(size_t)rowB * 4 + (mr - 4)] = acce1[i];
            }
        }
    } else {
        // y_h = sum_f h[row, 32h..32h+31] * pW[...]; feature f = mr + c*16
        float pw[8];
#pragma unroll
        for (int c = 0; c < 8; ++c) pw[c] = pW[mr + c * 16];
#pragma unroll
        for (int i = 0; i < 4; ++i) {
            int rowA = m0 + quad * 4 + i;
            {
                float y[4];
#pragma unroll
                for (int h = 0; h < 4; ++h)
                    y[h] = acc0[2 * h][i] * pw[2 * h] + acc0[2 * h + 1][i] * pw[2 * h + 1];
#pragma unroll
                for (int d = 1; d < 16; d <<= 1) {
#pragma unroll
                    for (int h = 0; h < 4; ++h) y[h] += __shfl_xor(y[h], d, 64);
                }
                if (rowA < N) {
                    if (mr < 4) {
                        float2 o; o.x = y[mr]; o.y = acce0[i];
                        *reinterpret_cast<float2*>(&yel[(size_t)rowA * 8 + mr * 2]) = o;
                    } else if (mr < 8) {
                        er[(size_t)rowA * 4 + (mr - 4)] = acce0[i];
                    }
                }
            }
            int rowB = m0 + 16 + quad * 4 + i;
            {
                float y[4];
#pragma unroll
                for (int h = 0; h < 4; ++h)
                    y[h] = acc1[2 * h][i] * pw[2 * h] + acc1[2 * h + 1][i] * pw[2 * h + 1];
#pragma unroll
                for (int d = 1; d < 16; d <<= 1) {
#pragma unroll
                    for (int h = 0; h < 4; ++h) y[h] += __shfl_xor(y[h], d, 64);
                }
                if (rowB < N) {
                    if (mr < 4) {
                        float2 o; o.x = y[mr]; o.y = acce1[i];
                        *reinterpret_cast<float2*>(&yel[(size_t)rowB * 8 + mr * 2]) = o;
                    } else if (mr < 8) {
                        er[(size_t)rowB * 4 + (mr - 4)] = acce1[i];
                    }
                }
            }
        }
    }
}

// ---------------------------------------------------------------------------
// MIDDLE-layer aggregation — depth-2 two-stream pipeline (at the random
// 256B-gather fabric ceiling, ~2.4TB/s L2-miss service rate).
__global__ __launch_bounds__(256) void agg_mid_kernel(
    const unsigned short* __restrict__ hb, const float* __restrict__ el,
    const float* __restrict__ er, const int* __restrict__ rowp,
    const int* __restrict__ col, const float* __restrict__ bias,
    unsigned short* __restrict__ xout, int N)
{
    const int lane = threadIdx.x & 63;
    const int q    = lane >> 4;
    const int l16  = lane & 15;
    const int v    = blockIdx.x * 16 + (threadIdx.x >> 6) * 4 + q;
    if (v >= N) return;

    const int r0 = rowp[v], r1 = rowp[v + 1];
    const int head = l16 >> 2;
    const int f0   = l16 * 8;
    const float erq = er[(size_t)v * 4 + head];
    const float el_self = el[(size_t)v * 4 + head];
    const float mref = leaky02(el_self + erq);

    float s = 0.f;
    float acc[8];
#pragma unroll
    for (int k = 0; k < 8; ++k) acc[k] = 0.f;

    // prologue: A holds edge r0 (self loop, col[r0]==v), B holds edge r0+1
    float elA = el_self;
    u16x8 hvA = *reinterpret_cast<const u16x8*>(&hb[(size_t)v * 128 + f0]);
    int jB = (r0 + 1 < r1) ? r0 + 1 : r1 - 1;
    int uB = col[jB];
    float elB = el[(size_t)uB * 4 + head];
    u16x8 hvB = *reinterpret_cast<const u16x8*>(&hb[(size_t)uB * 128 + f0]);

    for (int j = r0; j < r1; j += 2) {
        // prefetch A-stream edge j+2 (clamped to a valid edge)
        int jA2 = (j + 2 < r1) ? j + 2 : r1 - 1;
        int uA2 = col[jA2];
        float elA2 = el[(size_t)uA2 * 4 + head];
        u16x8 hvA2 = *reinterpret_cast<const u16x8*>(&hb[(size_t)uA2 * 128 + f0]);

        // compute edge j from A state (its load was issued 2 edges ago)
        {
            float e = leaky02(elA + erq);
            float d = fminf(e - mref, 80.f);
            float p = __expf(d);
            s += p;
#pragma unroll
            for (int k = 0; k < 8; ++k) acc[k] += p * bf2f(hvA[k]);
        }

        if (j + 1 < r1) {
            // prefetch B-stream edge j+3
            int jB2 = (j + 3 < r1) ? j + 3 : r1 - 1;
            int uB2 = col[jB2];
            float elB2 = el[(size_t)uB2 * 4 + head];
            u16x8 hvB2 = *reinterpret_cast<const u16x8*>(&hb[(size_t)uB2 * 128 + f0]);

            // compute edge j+1 from B state
            float e = leaky02(elB + erq);
            float d = fminf(e - mref, 80.f);
            float p = __expf(d);
            s += p;
#pragma unroll
            for (int k = 0; k < 8; ++k) acc[k] += p * bf2f(hvB[k]);

            elB = elB2; hvB = hvB2;
        }
        elA = elA2; hvA = hvA2;
    }
    const float is = 1.f / s;

    float4 b0 = *reinterpret_cast<const float4*>(&bias[f0]);
    float4 b1 = *reinterpret_cast<const float4*>(&bias[f0 + 4]);
    const float bb[8] = {b0.x, b0.y, b0.z, b0.w, b1.x, b1.y, b1.z, b1.w};

    u16x8 o;
#pragma unroll
    for (int k = 0; k < 8; ++k) o[k] = f2bf(leaky01(acc[k] * is + bb[k]));
    *reinterpret_cast<u16x8*>(&xout[(size_t)v * 128 + f0]) = o;
}

// ---------------------------------------------------------------------------
// LAST-layer aggregation — edge-parallel across the 4 lanes of each
// (vertex,head) group; merge is 2 scalars (S, A) x 2 shfl_xor.
__global__ __launch_bounds__(256) void agg2_kernel(
    const float* __restrict__ yel, const float* __restrict__ er,
    const int* __restrict__ rowp, const int* __restrict__ col,
    const float* __restrict__ prm, float* __restrict__ logits, int N)
{
    const int lane = threadIdx.x & 63;
    const int q    = lane >> 4;
    const int l16  = lane & 15;
    const int v    = blockIdx.x * 16 + (threadIdx.x >> 6) * 4 + q;
    if (v >= N) return;

    const int r0 = rowp[v], r1 = rowp[v + 1];
    const int head = l16 >> 2;
    const int e4   = l16 & 3;
    const float erq = er[(size_t)v * 4 + head];

    float2 selfy = *reinterpret_cast<const float2*>(&yel[(size_t)v * 8 + head * 2]);
    const float mref = leaky02(selfy.y + erq);   // self-loop e (col[r0]==v)

    float S = 0.f, A = 0.f;
    for (int j = r0 + e4; j < r1; j += 4) {
        int u = col[j];
        float2 c = *reinterpret_cast<const float2*>(&yel[(size_t)u * 8 + head * 2]);
        float e = leaky02(c.y + erq);
        float d = fminf(e - mref, 80.f);
        float p = __expf(d);
        S += p; A += p * c.x;
    }
    // quad-reduce within head group, then sum the 4 heads
    S += __shfl_xor(S, 1, 64); S += __shfl_xor(S, 2, 64);
    A += __shfl_xor(A, 1, 64); A += __shfl_xor(A, 2, 64);
    float part = A / S;
    part += __shfl_xor(part, 4, 64);
    part += __shfl_xor(part, 8, 64);
    if (l16 == 0) logits[v] = part + prm[16];
}

// ---------------------------------------------------------------------------
extern "C" void kernel_launch(void* const* d_in, const int* in_sizes, int n_in,
                              void* d_out, int out_size, void* d_ws, size_t ws_size,
                              hipStream_t stream)
{
    const float* weights = (const float*)d_in[0];
    const float* lin_W   = (const float*)d_in[1];
    const float* lin_b   = (const float*)d_in[2];
    const float* fc_W    = (const float*)d_in[3];
    const float* attn_l  = (const float*)d_in[4];
    const float* attn_r  = (const float*)d_in[5];
    const float* conv_b  = (const float*)d_in[6];
    const float* pred_W  = (const float*)d_in[7];
    const float* pred_b  = (const float*)d_in[8];
    const int*   src     = (const int*)d_in[9];
    const int*   dst     = (const int*)d_in[10];

    const int N = in_sizes[0];
    const int E = in_sizes[9];
    const int NB = (N + 1023) / 1024;   // tiles of 1024 (also CSR grid)

    // workspace layout (16B-aligned sections)
    unsigned short* xb = (unsigned short*)d_ws;                    // N*128 bf16 (pre-activated)
    unsigned short* hb = xb + (size_t)N * 128;                     // N*128 bf16
    float* el  = (float*)(hb + (size_t)N * 128);                   // N*4
    float* er  = el + (size_t)N * 4;                               // N*4
    float* yel = er + (size_t)N * 4;                               // N*8 {y,el} per head
    float* c1  = yel + (size_t)N * 8;                              // 128
    float* c2  = c1 + 128;                                         // 128
    float* prm = c2 + 128;                                         // 32
    short* Whs = (short*)(prm + 32);                               // 2*16384 bf16 (packed)
    short* Wls = Whs + 2 * 16384;                                  // 2*16384 bf16 (packed)
    short* Mhs = Wls + 2 * 16384;                                  // 2*2048 bf16 (Mext hi)
    short* Mls = Mhs + 2 * 2048;                                   // 2*2048 bf16 (Mext lo)
    int*   deg  = (int*)(Mls + 2 * 2048);                          // N
    int*   rowp = deg + N;                                         // N+1
    int*   slot = rowp + (N + 1);                                  // E
    int*   col  = slot + E;                                        // E+N
    int*   bsum = col + (E + N);                                   // NB
    int*   bpre = bsum + NB;                                       // NB

    // One launch: all prep + full CSR build (was 6 launches)
    csr_prep_kernel<<<NB, 1024, 0, stream>>>(
        deg, N, fc_W, attn_l, attn_r, Whs, Wls, Mhs, Mls,
        lin_W, lin_b, conv_b + 2 * 128, pred_W, pred_b, c1, c2, prm,
        src, dst, slot, E, bsum, bpre, rowp, col);

    // Layer 0: rank-1 aggregation straight from w (no h0 materialization)
    agg0_kernel<<<(N + 15) / 16, 256, 0, stream>>>(
        weights, c1, c2, prm, rowp, col, conv_b, xb, N);

    // Layer 1: gemm (mode 0) + full-gather aggregation
    gemm_mfma_kernel<<<(N + 127) / 128, 256, 0, stream>>>(
        xb, Whs, Wls, Mhs, Mls, hb, el, er, pred_W, yel, N, 0);
    agg_mid_kernel<<<(N + 15) / 16, 256, 0, stream>>>(
        hb, el, er, rowp, col, conv_b + 128, xb, N);

    // Layer 2: gemm (mode 1: y=h.pW + el packed) + light aggregation
    gemm_mfma_kernel<<<(N + 127) / 128, 256, 0, stream>>>(
        xb, Whs + 16384, Wls + 16384, Mhs + 2048, Mls + 2048,
        hb, el, er, pred_W, yel, N, 1);
    agg2_kernel<<<(N + 15) / 16, 256, 0, stream>>>(
        yel, er, rowp, col, prm, (float*)d_out, N);
}

// Round 8
// 296.460 us; speedup vs baseline: 1.0382x; 1.0382x over previous
//
#include <hip/hip_runtime.h>
#include <hip/hip_bf16.h>
#include <math.h>

// Problem constants: N=100000, E=600000, D=128, H=4, F=32, L=3

__device__ __forceinline__ float leaky02(float x) {
    return x >= 0.f ? x : 0.2f * x;
}
__device__ __forceinline__ float leaky01(float x) {
    return x >= 0.f ? x : 0.01f * x;
}

// bf16 helpers (round-to-nearest-even)
__device__ __forceinline__ unsigned short f2bf(float f) {
    unsigned u = __float_as_uint(f);
    unsigned r = u + 0x7FFFu + ((u >> 16) & 1u);
    return (unsigned short)(r >> 16);
}
__device__ __forceinline__ float bf2f(unsigned short s) {
    return __uint_as_float(((unsigned)s) << 16);
}

typedef __attribute__((ext_vector_type(8))) short bf16x8;
typedef __attribute__((ext_vector_type(8))) unsigned short u16x8;
typedef __attribute__((ext_vector_type(4))) float f32x4;

// ---------------------------------------------------------------------------
// FUSED PREP (one launch; jobs mutually independent):
//   blocks [0, nbi)   : deg[i]=1 init + W split into bf16 hi/lo (packed)
//   blocks nbi, nbi+1 : Mext rows for layers 1,2
//   block  nbi+2      : layer-0 rank-1 constants + epilogue constant
// Also zeroes the scan base counter.
__global__ __launch_bounds__(1024) void prep_kernel(
    int* __restrict__ deg, int N,
    const float* __restrict__ fc_W, const float* __restrict__ attn_l,
    const float* __restrict__ attn_r,
    short* __restrict__ Wh, short* __restrict__ Wl,
    short* __restrict__ Mh, short* __restrict__ Ml,
    const float* __restrict__ lW, const float* __restrict__ lb,
    const float* __restrict__ cb2, const float* __restrict__ pW,
    const float* __restrict__ pb,
    float* __restrict__ c1, float* __restrict__ c2, float* __restrict__ prm,
    int* __restrict__ base_ctr)
{
    const int nbi = (N + 1023) >> 10;
    const int b = blockIdx.x;
    const int t = threadIdx.x;
    if (b == 0 && t == 0) *base_ctr = 0;

    if (b < nbi) {
        int i = b * 1024 + t;
        if (i < N) deg[i] = 1;
        if (i < 2 * 16384) {
            const float* W = fc_W + 16384;   // layers 1,2
            int l    = i >> 14;
            int p    = i & 16383;
            int j    = p & 7;
            int lane = (p >> 3) & 63;
            int c    = (p >> 9) & 7;
            int kk   = p >> 12;
            int mr   = lane & 15;
            int quad = lane >> 4;
            int row  = c * 16 + mr;
            int d    = kk * 32 + quad * 8 + j;
            float f = W[(size_t)l * 16384 + row * 128 + d];
            unsigned short hi = f2bf(f);
            Wh[i] = (short)hi;
            Wl[i] = (short)f2bf(f - bf2f(hi));
        }
    } else if (b < nbi + 2) {
        int l = b - nbi;
        const float* W  = fc_W + (size_t)(l + 1) * 16384;
        const float* al = attn_l + (l + 1) * 128;
        const float* ar = attn_r + (l + 1) * 128;
        short* mh = Mh + (size_t)l * 16 * 128;
        short* ml = Ml + (size_t)l * 16 * 128;
        int r = t >> 7;                       // 0..7
        int d = t & 127;
        int hh = r & 3;
        const float* av = (r < 4) ? al : ar;
        float s = 0.f;
#pragma unroll
        for (int f = 0; f < 32; ++f)
            s += W[(size_t)(hh * 32 + f) * 128 + d] * av[hh * 32 + f];
        unsigned short hi = f2bf(s);
        mh[r * 128 + d] = (short)hi;
        ml[r * 128 + d] = (short)f2bf(s - bf2f(hi));
        mh[(r + 8) * 128 + d] = 0;            // zero rows 8..15
        ml[(r + 8) * 128 + d] = 0;
    } else {
        __shared__ float sh1[128], sh2[128], sh3[128], sh4[128], sh5[128];
        const float* W0 = fc_W;
        const float* al = attn_l;
        const float* ar = attn_r;
        int j = t >> 3, sub = t & 7;
        float s1 = 0.f, s2 = 0.f;
        int d0 = sub * 16;
#pragma unroll
        for (int k = 0; k < 16; ++k) {
            float wv = W0[j * 128 + d0 + k];
            s1 += lW[d0 + k] * wv;
            s2 += lb[d0 + k] * wv;
        }
#pragma unroll
        for (int m = 1; m <= 4; m <<= 1) {
            s1 += __shfl_xor(s1, m, 64);
            s2 += __shfl_xor(s2, m, 64);
        }
        if (sub == 0) {
            c1[j] = s1; c2[j] = s2;
            sh1[j] = s1 * al[j]; sh2[j] = s2 * al[j];
            sh3[j] = s1 * ar[j]; sh4[j] = s2 * ar[j];
            sh5[j] = cb2[j] * pW[j];
        }
        __syncthreads();
        if (t < 4) {
            float p = 0.f, q = 0.f, r = 0.f, s = 0.f;
            for (int f = 0; f < 32; ++f) {
                p += sh1[t * 32 + f]; q += sh2[t * 32 + f];
                r += sh3[t * 32 + f]; s += sh4[t * 32 + f];
            }
            prm[t] = p; prm[4 + t] = q; prm[8 + t] = r; prm[12 + t] = s;
        }
        if (t == 0) {
            float cs = 0.f;
            for (int k = 0; k < 128; ++k) cs += sh5[k];
            prm[16] = cs + pb[0];
        }
    }
}

// slot[i] = old count (>=1 because self loop holds slot 0)
__global__ __launch_bounds__(256) void deg_count_slot_kernel(
    const int* __restrict__ dst, int* __restrict__ deg,
    int* __restrict__ slot, int E)
{
    int i = blockIdx.x * 256 + threadIdx.x;
    if (i < E) slot[i] = atomicAdd(&deg[dst[i]], 1);
}

// ---------------------------------------------------------------------------
// SINGLE-KERNEL scan: per-tile (1024) inclusive scan + ONE atomicAdd for
// the tile base. Tile bases are order-nondeterministic, but each vertex's
// [rowp[v], rowp[v]+deg[v]) range is self-contained (aggregators use deg,
// not rowp[v+1]) and its slot layout is unchanged -> output bit-identical.
__global__ __launch_bounds__(1024) void scan_kernel(
    const int* __restrict__ deg, int* __restrict__ base_ctr,
    int* __restrict__ rowp, int* __restrict__ col, int N)
{
    __shared__ int sh[1024];
    __shared__ int sbase;
    int b = blockIdx.x, t = threadIdx.x;
    int i = b * 1024 + t;
    int v = (i < N) ? deg[i] : 0;
    sh[t] = v;
    __syncthreads();
    for (int off = 1; off < 1024; off <<= 1) {
        int u = (t >= off) ? sh[t - off] : 0;
        __syncthreads();
        sh[t] += u;
        __syncthreads();
    }
    if (t == 1023) sbase = atomicAdd(base_ctr, sh[1023]);
    __syncthreads();
    int pre = sbase + sh[t] - v;
    if (i < N) {
        rowp[i] = pre;
        col[pre] = i;   // self loop at slot 0
    }
}

// atomic-free scatter: position fully determined by rowp + recorded slot
__global__ __launch_bounds__(256) void scatter2_kernel(
    const int* __restrict__ src, const int* __restrict__ dst,
    const int* __restrict__ slot, const int* __restrict__ rowp,
    int* __restrict__ col, int E)
{
    int i = blockIdx.x * 256 + threadIdx.x;
    if (i < E) col[rowp[dst[i]] + slot[i]] = src[i];
}

// ---------------------------------------------------------------------------
// FUSED layer-0 aggregation + layer-1 MFMA gemm. Phase A computes the
// block's 128 x-rows (rank-1 agg, edge-parallel over 4 lanes/head) into a
// padded LDS tile; Phase B is the unchanged gemm (mode 0) reading its
// A-fragments from LDS. gemm block reads ONLY its own rows -> block-local
// dependency -> __syncthreads suffices (no grid barrier, no xb global).
__global__ __launch_bounds__(256) void l0g1_kernel(
    const float* __restrict__ w, const float* __restrict__ c1,
    const float* __restrict__ c2, const float* __restrict__ prm,
    const int* __restrict__ rowp, const int* __restrict__ deg,
    const int* __restrict__ col, const float* __restrict__ bias,
    const short* __restrict__ Wh, const short* __restrict__ Wl,
    const short* __restrict__ Mh, const short* __restrict__ Ml,
    unsigned short* __restrict__ hb, float* __restrict__ el,
    float* __restrict__ er, int N)
{
    __shared__ unsigned short xs[128][136];   // +8 pad: uniform bank spread
    const int t    = threadIdx.x;
    const int lane = t & 63;
    const int wv   = t >> 6;
    const int q    = lane >> 4;
    const int l16  = lane & 15;
    const int head = l16 >> 2;
    const int e4   = l16 & 3;
    const int f0   = l16 * 8;
    const int vbase = blockIdx.x * 128;

    // ---- Phase A: rank-1 layer-0 aggregation into LDS
    const float pl = prm[head],     ql = prm[4 + head];
    const float pr = prm[8 + head], qr = prm[12 + head];
    float4 a0v = *reinterpret_cast<const float4*>(&c1[f0]);
    float4 a1v = *reinterpret_cast<const float4*>(&c1[f0 + 4]);
    float4 g0v = *reinterpret_cast<const float4*>(&c2[f0]);
    float4 g1v = *reinterpret_cast<const float4*>(&c2[f0 + 4]);
    float4 b0v = *reinterpret_cast<const float4*>(&bias[f0]);
    float4 b1v = *reinterpret_cast<const float4*>(&bias[f0 + 4]);
    const float aa[8] = {a0v.x, a0v.y, a0v.z, a0v.w, a1v.x, a1v.y, a1v.z, a1v.w};
    const float gg[8] = {g0v.x, g0v.y, g0v.z, g0v.w, g1v.x, g1v.y, g1v.z, g1v.w};
    const float bb[8] = {b0v.x, b0v.y, b0v.z, b0v.w, b1v.x, b1v.y, b1v.z, b1v.w};

#pragma unroll
    for (int p = 0; p < 8; ++p) {
        const int lr = p * 16 + wv * 4 + q;
        const int v  = vbase + lr;
        u16x8 o;
        if (v < N) {
            const int r0 = rowp[v];
            const int r1 = r0 + deg[v];
            const float wvx  = w[v];
            const float erq  = wvx * pr + qr;
            const float mref = leaky02(wvx * pl + ql + erq);
            float S = 0.f, Sw = 0.f;
            for (int j = r0 + e4; j < r1; j += 4) {
                int u = col[j];
                float wu = w[u];
                float e = leaky02(wu * pl + ql + erq);
                float d = fminf(e - mref, 80.f);
                float pp = __expf(d);
                S += pp; Sw += pp * wu;
            }
            S  += __shfl_xor(S, 1, 64);  S  += __shfl_xor(S, 2, 64);
            Sw += __shfl_xor(Sw, 1, 64); Sw += __shfl_xor(Sw, 2, 64);
            const float tt = Sw / S;
#pragma unroll
            for (int k = 0; k < 8; ++k)
                o[k] = f2bf(leaky01(tt * aa[k] + gg[k] + bb[k]));
        } else {
#pragma unroll
            for (int k = 0; k < 8; ++k) o[k] = 0;
        }
        *reinterpret_cast<u16x8*>(&xs[lr][f0]) = o;
    }
    __syncthreads();

    // ---- Phase B: MFMA gemm (mode 0) from LDS
    const int m0   = vbase + wv * 32;
    const int mr   = lane & 15;
    const int quad = lane >> 4;

    f32x4 acc0[8], acc1[8], acce0, acce1;
#pragma unroll
    for (int c = 0; c < 8; ++c) {
        acc0[c] = (f32x4){0.f, 0.f, 0.f, 0.f};
        acc1[c] = (f32x4){0.f, 0.f, 0.f, 0.f};
    }
    acce0 = (f32x4){0.f, 0.f, 0.f, 0.f};
    acce1 = (f32x4){0.f, 0.f, 0.f, 0.f};

#pragma unroll
    for (int kk = 0; kk < 4; ++kk) {
        bf16x8 a0 = *reinterpret_cast<const bf16x8*>(&xs[wv * 32 + mr][quad * 8 + kk * 32]);
        bf16x8 a1 = *reinterpret_cast<const bf16x8*>(&xs[wv * 32 + 16 + mr][quad * 8 + kk * 32]);

        const int kb = kk * 32 + quad * 8;
        bf16x8 bh[8], bl[8];
#pragma unroll
        for (int c = 0; c < 8; ++c) {
            const size_t wo = (size_t)((kk * 8 + c) * 64 + lane) * 8;
            bh[c] = *reinterpret_cast<const bf16x8*>(Wh + wo);
            bl[c] = *reinterpret_cast<const bf16x8*>(Wl + wo);
        }
        bf16x8 eh = *reinterpret_cast<const bf16x8*>(Mh + (size_t)mr * 128 + kb);
        bf16x8 eo = *reinterpret_cast<const bf16x8*>(Ml + (size_t)mr * 128 + kb);
#pragma unroll
        for (int c = 0; c < 8; ++c) {
            acc0[c] = __builtin_amdgcn_mfma_f32_16x16x32_bf16(a0, bh[c], acc0[c], 0, 0, 0);
            acc0[c] = __builtin_amdgcn_mfma_f32_16x16x32_bf16(a0, bl[c], acc0[c], 0, 0, 0);
            acc1[c] = __builtin_amdgcn_mfma_f32_16x16x32_bf16(a1, bh[c], acc1[c], 0, 0, 0);
            acc1[c] = __builtin_amdgcn_mfma_f32_16x16x32_bf16(a1, bl[c], acc1[c], 0, 0, 0);
        }
        acce0 = __builtin_amdgcn_mfma_f32_16x16x32_bf16(a0, eh, acce0, 0, 0, 0);
        acce0 = __builtin_amdgcn_mfma_f32_16x16x32_bf16(a0, eo, acce0, 0, 0, 0);
        acce1 = __builtin_amdgcn_mfma_f32_16x16x32_bf16(a1, eh, acce1, 0, 0, 0);
        acce1 = __builtin_amdgcn_mfma_f32_16x16x32_bf16(a1, eo, acce1, 0, 0, 0);
    }

#pragma unroll
    for (int i = 0; i < 4; ++i) {
        int rowA = m0 + quad * 4 + i;
        if (rowA < N) {
            unsigned short* hp = hb + (size_t)rowA * 128 + mr;
#pragma unroll
            for (int c = 0; c < 8; ++c) hp[c * 16] = f2bf(acc0[c][i]);
            if (mr < 4)       el[(size_t)rowA * 4 + mr]       = acce0[i];
            else if (mr < 8)  er[(size_t)rowA * 4 + (mr - 4)] = acce0[i];
        }
        int rowB = m0 + 16 + quad * 4 + i;
        if (rowB < N) {
            unsigned short* hp = hb + (size_t)rowB * 128 + mr;
#pragma unroll
            for (int c = 0; c < 8; ++c) hp[c * 16] = f2bf(acc1[c][i]);
            if (mr < 4)       el[(size_t)rowB * 4 + mr]       = acce1[i];
            else if (mr < 8)  er[(size_t)rowB * 4 + (mr - 4)] = acce1[i];
        }
    }
}

// ---------------------------------------------------------------------------
// FUSED middle aggregation + layer-2 MFMA gemm (mode 1: yel + er).
// Phase A: depth-2 pipelined 256B h-gathers (fabric-bound, unchanged) into
// LDS x tile. Phase B: gemm; epilogue packs yel {y = h.pW, el} + er.
// Race audit: hb/el gathers read layer-1 arrays written by the PREVIOUS
// kernel (never written here); er reads are own-block rows in Phase A and
// own-block writes in Phase B (syncthreads-ordered); yel is write-only.
__global__ __launch_bounds__(256) void midg2_kernel(
    const unsigned short* __restrict__ hb, const float* __restrict__ el,
    float* __restrict__ er, const int* __restrict__ rowp,
    const int* __restrict__ deg, const int* __restrict__ col,
    const float* __restrict__ bias,
    const short* __restrict__ Wh, const short* __restrict__ Wl,
    const short* __restrict__ Mh, const short* __restrict__ Ml,
    const float* __restrict__ pW, float* __restrict__ yel, int N)
{
    __shared__ unsigned short xs[128][136];
    const int t    = threadIdx.x;
    const int lane = t & 63;
    const int wv   = t >> 6;
    const int q    = lane >> 4;
    const int l16  = lane & 15;
    const int head = l16 >> 2;
    const int f0   = l16 * 8;
    const int vbase = blockIdx.x * 128;

    float4 b0v = *reinterpret_cast<const float4*>(&bias[f0]);
    float4 b1v = *reinterpret_cast<const float4*>(&bias[f0 + 4]);
    const float bb[8] = {b0v.x, b0v.y, b0v.z, b0v.w, b1v.x, b1v.y, b1v.z, b1v.w};

    // ---- Phase A: depth-2 two-stream gather aggregation into LDS
#pragma unroll
    for (int p = 0; p < 8; ++p) {
        const int lr = p * 16 + wv * 4 + q;
        const int v  = vbase + lr;
        u16x8 o;
        if (v < N) {
            const int r0 = rowp[v];
            const int r1 = r0 + deg[v];
            const float erq = er[(size_t)v * 4 + head];
            const float el_self = el[(size_t)v * 4 + head];
            const float mref = leaky02(el_self + erq);

            float s = 0.f;
            float acc[8];
#pragma unroll
            for (int k = 0; k < 8; ++k) acc[k] = 0.f;

            float elA = el_self;                    // col[r0] == v
            u16x8 hvA = *reinterpret_cast<const u16x8*>(&hb[(size_t)v * 128 + f0]);
            int jB = (r0 + 1 < r1) ? r0 + 1 : r1 - 1;
            int uB = col[jB];
            float elB = el[(size_t)uB * 4 + head];
            u16x8 hvB = *reinterpret_cast<const u16x8*>(&hb[(size_t)uB * 128 + f0]);

            for (int j = r0; j < r1; j += 2) {
                int jA2 = (j + 2 < r1) ? j + 2 : r1 - 1;
                int uA2 = col[jA2];
                float elA2 = el[(size_t)uA2 * 4 + head];
                u16x8 hvA2 = *reinterpret_cast<const u16x8*>(&hb[(size_t)uA2 * 128 + f0]);

                {
                    float e = leaky02(elA + erq);
                    float d = fminf(e - mref, 80.f);
                    float pp = __expf(d);
                    s += pp;
#pragma unroll
                    for (int k = 0; k < 8; ++k) acc[k] += pp * bf2f(hvA[k]);
                }
                if (j + 1 < r1) {
                    int jB2 = (j + 3 < r1) ? j + 3 : r1 - 1;
                    int uB2 = col[jB2];
                    float elB2 = el[(size_t)uB2 * 4 + head];
                    u16x8 hvB2 = *reinterpret_cast<const u16x8*>(&hb[(size_t)uB2 * 128 + f0]);

                    float e = leaky02(elB + erq);
                    float d = fminf(e - mref, 80.f);
                    float pp = __expf(d);
                    s += pp;
#pragma unroll
                    for (int k = 0; k < 8; ++k) acc[k] += pp * bf2f(hvB[k]);

                    elB = elB2; hvB = hvB2;
                }
                elA = elA2; hvA = hvA2;
            }
            const float is = 1.f / s;
#pragma unroll
            for (int k = 0; k < 8; ++k)
                o[k] = f2bf(leaky01(acc[k] * is + bb[k]));
        } else {
#pragma unroll
            for (int k = 0; k < 8; ++k) o[k] = 0;
        }
        *reinterpret_cast<u16x8*>(&xs[lr][f0]) = o;
    }
    __syncthreads();

    // ---- Phase B: MFMA gemm (mode 1) from LDS
    const int m0   = vbase + wv * 32;
    const int mr   = lane & 15;
    const int quad = lane >> 4;

    f32x4 acc0[8], acc1[8], acce0, acce1;
#pragma unroll
    for (int c = 0; c < 8; ++c) {
        acc0[c] = (f32x4){0.f, 0.f, 0.f, 0.f};
        acc1[c] = (f32x4){0.f, 0.f, 0.f, 0.f};
    }
    acce0 = (f32x4){0.f, 0.f, 0.f, 0.f};
    acce1 = (f32x4){0.f, 0.f, 0.f, 0.f};

#pragma unroll
    for (int kk = 0; kk < 4; ++kk) {
        bf16x8 a0 = *reinterpret_cast<const bf16x8*>(&xs[wv * 32 + mr][quad * 8 + kk * 32]);
        bf16x8 a1 = *reinterpret_cast<const bf16x8*>(&xs[wv * 32 + 16 + mr][quad * 8 + kk * 32]);

        const int kb = kk * 32 + quad * 8;
        bf16x8 bh[8], bl[8];
#pragma unroll
        for (int c = 0; c < 8; ++c) {
            const size_t wo = (size_t)((kk * 8 + c) * 64 + lane) * 8;
            bh[c] = *reinterpret_cast<const bf16x8*>(Wh + wo);
            bl[c] = *reinterpret_cast<const bf16x8*>(Wl + wo);
        }
        bf16x8 eh = *reinterpret_cast<const bf16x8*>(Mh + (size_t)mr * 128 + kb);
        bf16x8 eo = *reinterpret_cast<const bf16x8*>(Ml + (size_t)mr * 128 + kb);
#pragma unroll
        for (int c = 0; c < 8; ++c) {
            acc0[c] = __builtin_amdgcn_mfma_f32_16x16x32_bf16(a0, bh[c], acc0[c], 0, 0, 0);
            acc0[c] = __builtin_amdgcn_mfma_f32_16x16x32_bf16(a0, bl[c], acc0[c], 0, 0, 0);
            acc1[c] = __builtin_amdgcn_mfma_f32_16x16x32_bf16(a1, bh[c], acc1[c], 0, 0, 0);
            acc1[c] = __builtin_amdgcn_mfma_f32_16x16x32_bf16(a1, bl[c], acc1[c], 0, 0, 0);
        }
        acce0 = __builtin_amdgcn_mfma_f32_16x16x32_bf16(a0, eh, acce0, 0, 0, 0);
        acce0 = __builtin_amdgcn_mfma_f32_16x16x32_bf16(a0, eo, acce0, 0, 0, 0);
        acce1 = __builtin_amdgcn_mfma_f32_16x16x32_bf16(a1, eh, acce1, 0, 0, 0);
        acce1 = __builtin_amdgcn_mfma_f32_16x16x32_bf16(a1, eo, acce1, 0, 0, 0);
    }

    // epilogue: y_h = sum_f h[row, 32h..32h+31]*pW; feature f = mr + c*16
    float pw[8];
#pragma unroll
    for (int c = 0; c < 8; ++c) pw[c] = pW[mr + c * 16];
#pragma unroll
    for (int i = 0; i < 4; ++i) {
        int rowA = m0 + quad * 4 + i;
        {
            float y[4];
#pragma unroll
            for (int h = 0; h < 4; ++h)
                y[h] = acc0[2 * h][i] * pw[2 * h] + acc0[2 * h + 1][i] * pw[2 * h + 1];
#pragma unroll
            for (int d = 1; d < 16; d <<= 1) {
#pragma unroll
                for (int h = 0; h < 4; ++h) y[h] += __shfl_xor(y[h], d, 64);
            }
            if (rowA < N) {
                if (mr < 4) {
                    float2 o; o.x = y[mr]; o.y = acce0[i];
                    *reinterpret_cast<float2*>(&yel[(size_t)rowA * 8 + mr * 2]) = o;
                } else if (mr < 8) {
                    er[(size_t)rowA * 4 + (mr - 4)] = acce0[i];
                }
            }
        }
        int rowB = m0 + 16 + quad * 4 + i;
        {
            float y[4];
#pragma unroll
            for (int h = 0; h < 4; ++h)
                y[h] = acc1[2 * h][i] * pw[2 * h] + acc1[2 * h + 1][i] * pw[2 * h + 1];
#pragma unroll
            for (int d = 1; d < 16; d <<= 1) {
#pragma unroll
                for (int h = 0; h < 4; ++h) y[h] += __shfl_xor(y[h], d, 64);
            }
            if (rowB < N) {
                if (mr < 4) {
                    float2 o; o.x = y[mr]; o.y = acce1[i];
                    *reinterpret_cast<float2*>(&yel[(size_t)rowB * 8 + mr * 2]) = o;
                } else if (mr < 8) {
                    er[(size_t)rowB * 4 + (mr - 4)] = acce1[i];
                }
            }
        }
    }
}

// ---------------------------------------------------------------------------
// LAST-layer aggregation — edge-parallel across the 4 lanes of each
// (vertex,head) group; merge is 2 scalars (S, A) x 2 shfl_xor.
__global__ __launch_bounds__(256) void agg2_kernel(
    const float* __restrict__ yel, const float* __restrict__ er,
    const int* __restrict__ rowp, const int* __restrict__ deg,
    const int* __restrict__ col, const float* __restrict__ prm,
    float* __restrict__ logits, int N)
{
    const int lane = threadIdx.x & 63;
    const int q    = lane >> 4;
    const int l16  = lane & 15;
    const int v    = blockIdx.x * 16 + (threadIdx.x >> 6) * 4 + q;
    if (v >= N) return;

    const int r0 = rowp[v];
    const int r1 = r0 + deg[v];
    const int head = l16 >> 2;
    const int e4   = l16 & 3;
    const float erq = er[(size_t)v * 4 + head];

    float2 selfy = *reinterpret_cast<const float2*>(&yel[(size_t)v * 8 + head * 2]);
    const float mref = leaky02(selfy.y + erq);   // self-loop e (col[r0]==v)

    float S = 0.f, A = 0.f;
    for (int j = r0 + e4; j < r1; j += 4) {
        int u = col[j];
        float2 c = *reinterpret_cast<const float2*>(&yel[(size_t)u * 8 + head * 2]);
        float e = leaky02(c.y + erq);
        float d = fminf(e - mref, 80.f);
        float p = __expf(d);
        S += p; A += p * c.x;
    }
    S += __shfl_xor(S, 1, 64); S += __shfl_xor(S, 2, 64);
    A += __shfl_xor(A, 1, 64); A += __shfl_xor(A, 2, 64);
    float part = A / S;
    part += __shfl_xor(part, 4, 64);
    part += __shfl_xor(part, 8, 64);
    if (l16 == 0) logits[v] = part + prm[16];
}

// ---------------------------------------------------------------------------
extern "C" void kernel_launch(void* const* d_in, const int* in_sizes, int n_in,
                              void* d_out, int out_size, void* d_ws, size_t ws_size,
                              hipStream_t stream)
{
    const float* weights = (const float*)d_in[0];
    const float* lin_W   = (const float*)d_in[1];
    const float* lin_b   = (const float*)d_in[2];
    const float* fc_W    = (const float*)d_in[3];
    const float* attn_l  = (const float*)d_in[4];
    const float* attn_r  = (const float*)d_in[5];
    const float* conv_b  = (const float*)d_in[6];
    const float* pred_W  = (const float*)d_in[7];
    const float* pred_b  = (const float*)d_in[8];
    const int*   src     = (const int*)d_in[9];
    const int*   dst     = (const int*)d_in[10];

    const int N = in_sizes[0];
    const int E = in_sizes[9];
    const int NB1024 = (N + 1023) / 1024;

    // workspace layout (16B-aligned sections)
    unsigned short* hb = (unsigned short*)d_ws;                    // N*128 bf16
    float* el  = (float*)(hb + (size_t)N * 128);                   // N*4
    float* er  = el + (size_t)N * 4;                               // N*4
    float* yel = er + (size_t)N * 4;                               // N*8 {y,el} per head
    float* c1  = yel + (size_t)N * 8;                              // 128
    float* c2  = c1 + 128;                                         // 128
    float* prm = c2 + 128;                                         // 32
    short* Whs = (short*)(prm + 32);                               // 2*16384 bf16 (packed)
    short* Wls = Whs + 2 * 16384;                                  // 2*16384 bf16 (packed)
    short* Mhs = Wls + 2 * 16384;                                  // 2*2048 bf16 (Mext hi)
    short* Mls = Mhs + 2 * 2048;                                   // 2*2048 bf16 (Mext lo)
    int*   deg  = (int*)(Mls + 2 * 2048);                          // N
    int*   rowp = deg + N;                                         // N+1
    int*   slot = rowp + (N + 1);                                  // E
    int*   col  = slot + E;                                        // E+N
    int*   bctr = col + (E + N);                                   // 1 (scan base)

    // 1. fused prep (also zeroes scan base counter)
    prep_kernel<<<NB1024 + 3, 1024, 0, stream>>>(
        deg, N, fc_W, attn_l, attn_r, Whs, Wls, Mhs, Mls,
        lin_W, lin_b, conv_b + 2 * 128, pred_W, pred_b, c1, c2, prm, bctr);

    // 2. per-dst count (slot record)
    deg_count_slot_kernel<<<(E + 255) / 256, 256, 0, stream>>>(dst, deg, slot, E);

    // 3. single-kernel scan (atomic tile base) + self-loop col
    scan_kernel<<<NB1024, 1024, 0, stream>>>(deg, bctr, rowp, col, N);

    // 4. edge scatter
    scatter2_kernel<<<(E + 255) / 256, 256, 0, stream>>>(src, dst, slot, rowp, col, E);

    // 5. fused layer-0 agg + layer-1 gemm (x lives in LDS only)
    l0g1_kernel<<<(N + 127) / 128, 256, 0, stream>>>(
        weights, c1, c2, prm, rowp, deg, col, conv_b,
        Whs, Wls, Mhs, Mls, hb, el, er, N);

    // 6. fused middle agg + layer-2 gemm (yel/er out)
    midg2_kernel<<<(N + 127) / 128, 256, 0, stream>>>(
        hb, el, er, rowp, deg, col, conv_b + 128,
        Whs + 16384, Wls + 16384, Mhs + 2048, Mls + 2048, pred_W, yel, N);

    // 7. last aggregation -> logits
    agg2_kernel<<<(N + 15) / 16, 256, 0, stream>>>(
        yel, er, rowp, deg, col, prm, (float*)d_out, N);
}

// Round 9
// 248.212 us; speedup vs baseline: 1.2400x; 1.1944x over previous
//
#include <hip/hip_runtime.h>
#include <hip/hip_bf16.h>
#include <math.h>

// Problem constants: N=100000, E=600000, D=128, H=4, F=32, L=3

__device__ __forceinline__ float leaky02(float x) {
    return x >= 0.f ? x : 0.2f * x;
}
__device__ __forceinline__ float leaky01(float x) {
    return x >= 0.f ? x : 0.01f * x;
}

// bf16 helpers (round-to-nearest-even)
__device__ __forceinline__ unsigned short f2bf(float f) {
    unsigned u = __float_as_uint(f);
    unsigned r = u + 0x7FFFu + ((u >> 16) & 1u);
    return (unsigned short)(r >> 16);
}
__device__ __forceinline__ float bf2f(unsigned short s) {
    return __uint_as_float(((unsigned)s) << 16);
}

typedef __attribute__((ext_vector_type(8))) short bf16x8;
typedef __attribute__((ext_vector_type(8))) unsigned short u16x8;
typedef __attribute__((ext_vector_type(4))) float f32x4;

// ---------------------------------------------------------------------------
// FUSED PREP (one launch; jobs mutually independent):
//   blocks [0, nbi)   : deg[i]=1 init + W split into bf16 hi/lo (packed)
//   blocks nbi, nbi+1 : Mext rows for layers 1,2
//   block  nbi+2      : layer-0 rank-1 constants + epilogue constant
// Also zeroes the scan base counter.
__global__ __launch_bounds__(1024) void prep_kernel(
    int* __restrict__ deg, int N,
    const float* __restrict__ fc_W, const float* __restrict__ attn_l,
    const float* __restrict__ attn_r,
    short* __restrict__ Wh, short* __restrict__ Wl,
    short* __restrict__ Mh, short* __restrict__ Ml,
    const float* __restrict__ lW, const float* __restrict__ lb,
    const float* __restrict__ cb2, const float* __restrict__ pW,
    const float* __restrict__ pb,
    float* __restrict__ c1, float* __restrict__ c2, float* __restrict__ prm,
    int* __restrict__ base_ctr)
{
    const int nbi = (N + 1023) >> 10;
    const int b = blockIdx.x;
    const int t = threadIdx.x;
    if (b == 0 && t == 0) *base_ctr = 0;

    if (b < nbi) {
        int i = b * 1024 + t;
        if (i < N) deg[i] = 1;
        if (i < 2 * 16384) {
            const float* W = fc_W + 16384;   // layers 1,2
            int l    = i >> 14;
            int p    = i & 16383;
            int j    = p & 7;
            int lane = (p >> 3) & 63;
            int c    = (p >> 9) & 7;
            int kk   = p >> 12;
            int mr   = lane & 15;
            int quad = lane >> 4;
            int row  = c * 16 + mr;
            int d    = kk * 32 + quad * 8 + j;
            float f = W[(size_t)l * 16384 + row * 128 + d];
            unsigned short hi = f2bf(f);
            Wh[i] = (short)hi;
            Wl[i] = (short)f2bf(f - bf2f(hi));
        }
    } else if (b < nbi + 2) {
        int l = b - nbi;
        const float* W  = fc_W + (size_t)(l + 1) * 16384;
        const float* al = attn_l + (l + 1) * 128;
        const float* ar = attn_r + (l + 1) * 128;
        short* mh = Mh + (size_t)l * 16 * 128;
        short* ml = Ml + (size_t)l * 16 * 128;
        int r = t >> 7;                       // 0..7
        int d = t & 127;
        int hh = r & 3;
        const float* av = (r < 4) ? al : ar;
        float s = 0.f;
#pragma unroll
        for (int f = 0; f < 32; ++f)
            s += W[(size_t)(hh * 32 + f) * 128 + d] * av[hh * 32 + f];
        unsigned short hi = f2bf(s);
        mh[r * 128 + d] = (short)hi;
        ml[r * 128 + d] = (short)f2bf(s - bf2f(hi));
        mh[(r + 8) * 128 + d] = 0;            // zero rows 8..15
        ml[(r + 8) * 128 + d] = 0;
    } else {
        __shared__ float sh1[128], sh2[128], sh3[128], sh4[128], sh5[128];
        const float* W0 = fc_W;
        const float* al = attn_l;
        const float* ar = attn_r;
        int j = t >> 3, sub = t & 7;
        float s1 = 0.f, s2 = 0.f;
        int d0 = sub * 16;
#pragma unroll
        for (int k = 0; k < 16; ++k) {
            float wv = W0[j * 128 + d0 + k];
            s1 += lW[d0 + k] * wv;
            s2 += lb[d0 + k] * wv;
        }
#pragma unroll
        for (int m = 1; m <= 4; m <<= 1) {
            s1 += __shfl_xor(s1, m, 64);
            s2 += __shfl_xor(s2, m, 64);
        }
        if (sub == 0) {
            c1[j] = s1; c2[j] = s2;
            sh1[j] = s1 * al[j]; sh2[j] = s2 * al[j];
            sh3[j] = s1 * ar[j]; sh4[j] = s2 * ar[j];
            sh5[j] = cb2[j] * pW[j];
        }
        __syncthreads();
        if (t < 4) {
            float p = 0.f, q = 0.f, r = 0.f, s = 0.f;
            for (int f = 0; f < 32; ++f) {
                p += sh1[t * 32 + f]; q += sh2[t * 32 + f];
                r += sh3[t * 32 + f]; s += sh4[t * 32 + f];
            }
            prm[t] = p; prm[4 + t] = q; prm[8 + t] = r; prm[12 + t] = s;
        }
        if (t == 0) {
            float cs = 0.f;
            for (int k = 0; k < 128; ++k) cs += sh5[k];
            prm[16] = cs + pb[0];
        }
    }
}

// slot[i] = old count (>=1 because self loop holds slot 0)
__global__ __launch_bounds__(256) void deg_count_slot_kernel(
    const int* __restrict__ dst, int* __restrict__ deg,
    int* __restrict__ slot, int E)
{
    int i = blockIdx.x * 256 + threadIdx.x;
    if (i < E) slot[i] = atomicAdd(&deg[dst[i]], 1);
}

// ---------------------------------------------------------------------------
// SINGLE-KERNEL scan: per-tile (1024) inclusive scan + ONE atomicAdd for
// the tile base. Tile bases are order-nondeterministic, but each vertex's
// [rowp[v], rowp[v]+deg[v]) range is self-contained (aggregators use deg)
// and its slot layout is unchanged -> output bit-identical.
__global__ __launch_bounds__(1024) void scan_kernel(
    const int* __restrict__ deg, int* __restrict__ base_ctr,
    int* __restrict__ rowp, int* __restrict__ col, int N)
{
    __shared__ int sh[1024];
    __shared__ int sbase;
    int b = blockIdx.x, t = threadIdx.x;
    int i = b * 1024 + t;
    int v = (i < N) ? deg[i] : 0;
    sh[t] = v;
    __syncthreads();
    for (int off = 1; off < 1024; off <<= 1) {
        int u = (t >= off) ? sh[t - off] : 0;
        __syncthreads();
        sh[t] += u;
        __syncthreads();
    }
    if (t == 1023) sbase = atomicAdd(base_ctr, sh[1023]);
    __syncthreads();
    int pre = sbase + sh[t] - v;
    if (i < N) {
        rowp[i] = pre;
        col[pre] = i;   // self loop at slot 0
    }
}

// atomic-free scatter: position fully determined by rowp + recorded slot
__global__ __launch_bounds__(256) void scatter2_kernel(
    const int* __restrict__ src, const int* __restrict__ dst,
    const int* __restrict__ slot, const int* __restrict__ rowp,
    int* __restrict__ col, int E)
{
    int i = blockIdx.x * 256 + threadIdx.x;
    if (i < E) col[rowp[dst[i]] + slot[i]] = src[i];
}

// ---------------------------------------------------------------------------
// LAYER-0 aggregation via rank-1 identity — edge-parallel across the 4
// lanes of each (vertex,head) group. (R6 champion version; r1 via deg.)
__global__ __launch_bounds__(256) void agg0_kernel(
    const float* __restrict__ w, const float* __restrict__ c1,
    const float* __restrict__ c2, const float* __restrict__ prm,
    const int* __restrict__ rowp, const int* __restrict__ deg,
    const int* __restrict__ col, const float* __restrict__ bias,
    unsigned short* __restrict__ xout, int N)
{
    const int lane = threadIdx.x & 63;
    const int q    = lane >> 4;
    const int l16  = lane & 15;
    const int v    = blockIdx.x * 16 + (threadIdx.x >> 6) * 4 + q;
    if (v >= N) return;

    const int r0 = rowp[v];
    const int r1 = r0 + deg[v];
    const int head = l16 >> 2;
    const int e4   = l16 & 3;        // edge slot within head group
    const int f0   = l16 * 8;
    const float pl = prm[head],     ql = prm[4 + head];
    const float pr = prm[8 + head], qr = prm[12 + head];

    const float wv  = w[v];
    const float erq = wv * pr + qr;
    const float mref = leaky02(wv * pl + ql + erq);   // self-loop e

    float S = 0.f, Sw = 0.f;
    for (int j = r0 + e4; j < r1; j += 4) {
        int u = col[j];                                // (j==r0 -> u==v)
        float wu = w[u];
        float e = leaky02(wu * pl + ql + erq);
        float d = fminf(e - mref, 80.f);
        float p = __expf(d);
        S += p; Sw += p * wu;
    }
    // quad-reduce (lanes of a head group are 4 consecutive lanes)
    S  += __shfl_xor(S, 1, 64);  S  += __shfl_xor(S, 2, 64);
    Sw += __shfl_xor(Sw, 1, 64); Sw += __shfl_xor(Sw, 2, 64);
    const float t = Sw / S;

    float4 a0 = *reinterpret_cast<const float4*>(&c1[f0]);
    float4 a1 = *reinterpret_cast<const float4*>(&c1[f0 + 4]);
    float4 g0 = *reinterpret_cast<const float4*>(&c2[f0]);
    float4 g1 = *reinterpret_cast<const float4*>(&c2[f0 + 4]);
    float4 b0 = *reinterpret_cast<const float4*>(&bias[f0]);
    float4 b1 = *reinterpret_cast<const float4*>(&bias[f0 + 4]);
    const float aa[8] = {a0.x, a0.y, a0.z, a0.w, a1.x, a1.y, a1.z, a1.w};
    const float gg[8] = {g0.x, g0.y, g0.z, g0.w, g1.x, g1.y, g1.z, g1.w};
    const float bb[8] = {b0.x, b0.y, b0.z, b0.w, b1.x, b1.y, b1.z, b1.w};

    u16x8 o;
#pragma unroll
    for (int k = 0; k < 8; ++k)
        o[k] = f2bf(leaky01(t * aa[k] + gg[k] + bb[k]));
    *reinterpret_cast<u16x8*>(&xout[(size_t)v * 128 + f0]) = o;
}

// ---------------------------------------------------------------------------
// MFMA bf16 GEMM (layers 1,2) + fused el/er tile — 32 rows/wave,
// FRAGMENT-PACKED W. mode 0 (layer1): write hb + el + er.
// mode 1 (layer2): skip hb; write yel[row*8+h*2] = {y_h = h.pW_h, el_h} + er.
__global__ __launch_bounds__(256) void gemm_mfma_kernel(
    const unsigned short* __restrict__ xb, const short* __restrict__ Wh,
    const short* __restrict__ Wl, const short* __restrict__ Mh,
    const short* __restrict__ Ml, unsigned short* __restrict__ hb,
    float* __restrict__ el, float* __restrict__ er,
    const float* __restrict__ pW, float* __restrict__ yel,
    int N, int mode)
{
    const int lane = threadIdx.x & 63;
    const int wv   = threadIdx.x >> 6;
    const int m0   = blockIdx.x * 128 + wv * 32;  // 32 rows per wave
    const int mr   = lane & 15;
    const int quad = lane >> 4;

    int r0 = m0 + mr;      if (r0 > N - 1) r0 = N - 1;   // clamped load rows
    int r1 = m0 + 16 + mr; if (r1 > N - 1) r1 = N - 1;
    const unsigned short* xp0 = xb + (size_t)r0 * 128 + quad * 8;
    const unsigned short* xp1 = xb + (size_t)r1 * 128 + quad * 8;

    f32x4 acc0[8], acc1[8], acce0, acce1;
#pragma unroll
    for (int c = 0; c < 8; ++c) {
        acc0[c] = (f32x4){0.f, 0.f, 0.f, 0.f};
        acc1[c] = (f32x4){0.f, 0.f, 0.f, 0.f};
    }
    acce0 = (f32x4){0.f, 0.f, 0.f, 0.f};
    acce1 = (f32x4){0.f, 0.f, 0.f, 0.f};

#pragma unroll
    for (int kk = 0; kk < 4; ++kk) {
        bf16x8 a0 = *reinterpret_cast<const bf16x8*>(xp0 + kk * 32);
        bf16x8 a1 = *reinterpret_cast<const bf16x8*>(xp1 + kk * 32);

        const int kb = kk * 32 + quad * 8;
        bf16x8 bh[8], bl[8];
#pragma unroll
        for (int c = 0; c < 8; ++c) {
            const size_t wo = (size_t)((kk * 8 + c) * 64 + lane) * 8;
            bh[c] = *reinterpret_cast<const bf16x8*>(Wh + wo);
            bl[c] = *reinterpret_cast<const bf16x8*>(Wl + wo);
        }
        bf16x8 eh = *reinterpret_cast<const bf16x8*>(Mh + (size_t)mr * 128 + kb);
        bf16x8 eo = *reinterpret_cast<const bf16x8*>(Ml + (size_t)mr * 128 + kb);
#pragma unroll
        for (int c = 0; c < 8; ++c) {
            acc0[c] = __builtin_amdgcn_mfma_f32_16x16x32_bf16(a0, bh[c], acc0[c], 0, 0, 0);
            acc0[c] = __builtin_amdgcn_mfma_f32_16x16x32_bf16(a0, bl[c], acc0[c], 0, 0, 0);
            acc1[c] = __builtin_amdgcn_mfma_f32_16x16x32_bf16(a1, bh[c], acc1[c], 0, 0, 0);
            acc1[c] = __builtin_amdgcn_mfma_f32_16x16x32_bf16(a1, bl[c], acc1[c], 0, 0, 0);
        }
        acce0 = __builtin_amdgcn_mfma_f32_16x16x32_bf16(a0, eh, acce0, 0, 0, 0);
        acce0 = __builtin_amdgcn_mfma_f32_16x16x32_bf16(a0, eo, acce0, 0, 0, 0);
        acce1 = __builtin_amdgcn_mfma_f32_16x16x32_bf16(a1, eh, acce1, 0, 0, 0);
        acce1 = __builtin_amdgcn_mfma_f32_16x16x32_bf16(a1, eo, acce1, 0, 0, 0);
    }

    if (mode == 0) {
#pragma unroll
        for (int i = 0; i < 4; ++i) {
            int rowA = m0 + quad * 4 + i;
            if (rowA < N) {
                unsigned short* hp = hb + (size_t)rowA * 128 + mr;
#pragma unroll
                for (int c = 0; c < 8; ++c) hp[c * 16] = f2bf(acc0[c][i]);
                if (mr < 4)       el[(size_t)rowA * 4 + mr]       = acce0[i];
                else if (mr < 8)  er[(size_t)rowA * 4 + (mr - 4)] = acce0[i];
            }
            int rowB = m0 + 16 + quad * 4 + i;
            if (rowB < N) {
                unsigned short* hp = hb + (size_t)rowB * 128 + mr;
#pragma unroll
                for (int c = 0; c < 8; ++c) hp[c * 16] = f2bf(acc1[c][i]);
                if (mr < 4)       el[(size_t)rowB * 4 + mr]       = acce1[i];
                else if (mr < 8)  er[(size_t)rowB * 4 + (mr - 4)] = acce1[i];
            }
        }
    } else {
        // y_h = sum_f h[row, 32h..32h+31] * pW[...]; feature f = mr + c*16
        float pw[8];
#pragma unroll
        for (int c = 0; c < 8; ++c) pw[c] = pW[mr + c * 16];
#pragma unroll
        for (int i = 0; i < 4; ++i) {
            int rowA = m0 + quad * 4 + i;
            {
                float y[4];
#pragma unroll
                for (int h = 0; h < 4; ++h)
                    y[h] = acc0[2 * h][i] * pw[2 * h] + acc0[2 * h + 1][i] * pw[2 * h + 1];
#pragma unroll
                for (int d = 1; d < 16; d <<= 1) {
#pragma unroll
                    for (int h = 0; h < 4; ++h) y[h] += __shfl_xor(y[h], d, 64);
                }
                if (rowA < N) {
                    if (mr < 4) {
                        float2 o; o.x = y[mr]; o.y = acce0[i];
                        *reinterpret_cast<float2*>(&yel[(size_t)rowA * 8 + mr * 2]) = o;
                    } else if (mr < 8) {
                        er[(size_t)rowA * 4 + (mr - 4)] = acce0[i];
                    }
                }
            }
            int rowB = m0 + 16 + quad * 4 + i;
            {
                float y[4];
#pragma unroll
                for (int h = 0; h < 4; ++h)
                    y[h] = acc1[2 * h][i] * pw[2 * h] + acc1[2 * h + 1][i] * pw[2 * h + 1];
#pragma unroll
                for (int d = 1; d < 16; d <<= 1) {
#pragma unroll
                    for (int h = 0; h < 4; ++h) y[h] += __shfl_xor(y[h], d, 64);
                }
                if (rowB < N) {
                    if (mr < 4) {
                        float2 o; o.x = y[mr]; o.y = acce1[i];
                        *reinterpret_cast<float2*>(&yel[(size_t)rowB * 8 + mr * 2]) = o;
                    } else if (mr < 8) {
                        er[(size_t)rowB * 4 + (mr - 4)] = acce1[i];
                    }
                }
            }
        }
    }
}

// ---------------------------------------------------------------------------
// MIDDLE-layer aggregation — depth-2 two-stream pipeline, standalone (high
// occupancy is essential: R8's gemm-fusion cut occupancy 59%->16% and
// collapsed gather BW 3.0->0.9 TB/s). At the random 256B-gather fabric
// ceiling (~2.4TB/s L2-miss service rate).
__global__ __launch_bounds__(256) void agg_mid_kernel(
    const unsigned short* __restrict__ hb, const float* __restrict__ el,
    const float* __restrict__ er, const int* __restrict__ rowp,
    const int* __restrict__ deg, const int* __restrict__ col,
    const float* __restrict__ bias, unsigned short* __restrict__ xout, int N)
{
    const int lane = threadIdx.x & 63;
    const int q    = lane >> 4;
    const int l16  = lane & 15;
    const int v    = blockIdx.x * 16 + (threadIdx.x >> 6) * 4 + q;
    if (v >= N) return;

    const int r0 = rowp[v];
    const int r1 = r0 + deg[v];
    const int head = l16 >> 2;
    const int f0   = l16 * 8;
    const float erq = er[(size_t)v * 4 + head];
    const float el_self = el[(size_t)v * 4 + head];
    const float mref = leaky02(el_self + erq);

    float s = 0.f;
    float acc[8];
#pragma unroll
    for (int k = 0; k < 8; ++k) acc[k] = 0.f;

    // prologue: A holds edge r0 (self loop, col[r0]==v), B holds edge r0+1
    float elA = el_self;
    u16x8 hvA = *reinterpret_cast<const u16x8*>(&hb[(size_t)v * 128 + f0]);
    int jB = (r0 + 1 < r1) ? r0 + 1 : r1 - 1;
    int uB = col[jB];
    float elB = el[(size_t)uB * 4 + head];
    u16x8 hvB = *reinterpret_cast<const u16x8*>(&hb[(size_t)uB * 128 + f0]);

    for (int j = r0; j < r1; j += 2) {
        // prefetch A-stream edge j+2 (clamped to a valid edge)
        int jA2 = (j + 2 < r1) ? j + 2 : r1 - 1;
        int uA2 = col[jA2];
        float elA2 = el[(size_t)uA2 * 4 + head];
        u16x8 hvA2 = *reinterpret_cast<const u16x8*>(&hb[(size_t)uA2 * 128 + f0]);

        // compute edge j from A state (its load was issued 2 edges ago)
        {
            float e = leaky02(elA + erq);
            float d = fminf(e - mref, 80.f);
            float p = __expf(d);
            s += p;
#pragma unroll
            for (int k = 0; k < 8; ++k) acc[k] += p * bf2f(hvA[k]);
        }

        if (j + 1 < r1) {
            // prefetch B-stream edge j+3
            int jB2 = (j + 3 < r1) ? j + 3 : r1 - 1;
            int uB2 = col[jB2];
            float elB2 = el[(size_t)uB2 * 4 + head];
            u16x8 hvB2 = *reinterpret_cast<const u16x8*>(&hb[(size_t)uB2 * 128 + f0]);

            // compute edge j+1 from B state
            float e = leaky02(elB + erq);
            float d = fminf(e - mref, 80.f);
            float p = __expf(d);
            s += p;
#pragma unroll
            for (int k = 0; k < 8; ++k) acc[k] += p * bf2f(hvB[k]);

            elB = elB2; hvB = hvB2;
        }
        elA = elA2; hvA = hvA2;
    }
    const float is = 1.f / s;

    float4 b0 = *reinterpret_cast<const float4*>(&bias[f0]);
    float4 b1 = *reinterpret_cast<const float4*>(&bias[f0 + 4]);
    const float bb[8] = {b0.x, b0.y, b0.z, b0.w, b1.x, b1.y, b1.z, b1.w};

    u16x8 o;
#pragma unroll
    for (int k = 0; k < 8; ++k) o[k] = f2bf(leaky01(acc[k] * is + bb[k]));
    *reinterpret_cast<u16x8*>(&xout[(size_t)v * 128 + f0]) = o;
}

// ---------------------------------------------------------------------------
// LAST-layer aggregation — edge-parallel across the 4 lanes of each
// (vertex,head) group; merge is 2 scalars (S, A) x 2 shfl_xor.
__global__ __launch_bounds__(256) void agg2_kernel(
    const float* __restrict__ yel, const float* __restrict__ er,
    const int* __restrict__ rowp, const int* __restrict__ deg,
    const int* __restrict__ col, const float* __restrict__ prm,
    float* __restrict__ logits, int N)
{
    const int lane = threadIdx.x & 63;
    const int q    = lane >> 4;
    const int l16  = lane & 15;
    const int v    = blockIdx.x * 16 + (threadIdx.x >> 6) * 4 + q;
    if (v >= N) return;

    const int r0 = rowp[v];
    const int r1 = r0 + deg[v];
    const int head = l16 >> 2;
    const int e4   = l16 & 3;
    const float erq = er[(size_t)v * 4 + head];

    float2 selfy = *reinterpret_cast<const float2*>(&yel[(size_t)v * 8 + head * 2]);
    const float mref = leaky02(selfy.y + erq);   // self-loop e (col[r0]==v)

    float S = 0.f, A = 0.f;
    for (int j = r0 + e4; j < r1; j += 4) {
        int u = col[j];
        float2 c = *reinterpret_cast<const float2*>(&yel[(size_t)u * 8 + head * 2]);
        float e = leaky02(c.y + erq);
        float d = fminf(e - mref, 80.f);
        float p = __expf(d);
        S += p; A += p * c.x;
    }
    S += __shfl_xor(S, 1, 64); S += __shfl_xor(S, 2, 64);
    A += __shfl_xor(A, 1, 64); A += __shfl_xor(A, 2, 64);
    float part = A / S;
    part += __shfl_xor(part, 4, 64);
    part += __shfl_xor(part, 8, 64);
    if (l16 == 0) logits[v] = part + prm[16];
}

// ---------------------------------------------------------------------------
extern "C" void kernel_launch(void* const* d_in, const int* in_sizes, int n_in,
                              void* d_out, int out_size, void* d_ws, size_t ws_size,
                              hipStream_t stream)
{
    const float* weights = (const float*)d_in[0];
    const float* lin_W   = (const float*)d_in[1];
    const float* lin_b   = (const float*)d_in[2];
    const float* fc_W    = (const float*)d_in[3];
    const float* attn_l  = (const float*)d_in[4];
    const float* attn_r  = (const float*)d_in[5];
    const float* conv_b  = (const float*)d_in[6];
    const float* pred_W  = (const float*)d_in[7];
    const float* pred_b  = (const float*)d_in[8];
    const int*   src     = (const int*)d_in[9];
    const int*   dst     = (const int*)d_in[10];

    const int N = in_sizes[0];
    const int E = in_sizes[9];
    const int NB1024 = (N + 1023) / 1024;

    // workspace layout (16B-aligned sections)
    unsigned short* xb = (unsigned short*)d_ws;                    // N*128 bf16 (pre-activated)
    unsigned short* hb = xb + (size_t)N * 128;                     // N*128 bf16
    float* el  = (float*)(hb + (size_t)N * 128);                   // N*4
    float* er  = el + (size_t)N * 4;                               // N*4
    float* yel = er + (size_t)N * 4;                               // N*8 {y,el} per head
    float* c1  = yel + (size_t)N * 8;                              // 128
    float* c2  = c1 + 128;                                         // 128
    float* prm = c2 + 128;                                         // 32
    short* Whs = (short*)(prm + 32);                               // 2*16384 bf16 (packed)
    short* Wls = Whs + 2 * 16384;                                  // 2*16384 bf16 (packed)
    short* Mhs = Wls + 2 * 16384;                                  // 2*2048 bf16 (Mext hi)
    short* Mls = Mhs + 2 * 2048;                                   // 2*2048 bf16 (Mext lo)
    int*   deg  = (int*)(Mls + 2 * 2048);                          // N
    int*   rowp = deg + N;                                         // N+1
    int*   slot = rowp + (N + 1);                                  // E
    int*   col  = slot + E;                                        // E+N
    int*   bctr = col + (E + N);                                   // 1 (scan base)

    // 1. fused prep (also zeroes scan base counter)
    prep_kernel<<<NB1024 + 3, 1024, 0, stream>>>(
        deg, N, fc_W, attn_l, attn_r, Whs, Wls, Mhs, Mls,
        lin_W, lin_b, conv_b + 2 * 128, pred_W, pred_b, c1, c2, prm, bctr);

    // 2. per-dst count (slot record)
    deg_count_slot_kernel<<<(E + 255) / 256, 256, 0, stream>>>(dst, deg, slot, E);

    // 3. single-kernel scan (atomic tile base) + self-loop col
    scan_kernel<<<NB1024, 1024, 0, stream>>>(deg, bctr, rowp, col, N);

    // 4. edge scatter
    scatter2_kernel<<<(E + 255) / 256, 256, 0, stream>>>(src, dst, slot, rowp, col, E);

    // 5. layer-0 rank-1 aggregation -> xb
    agg0_kernel<<<(N + 15) / 16, 256, 0, stream>>>(
        weights, c1, c2, prm, rowp, deg, col, conv_b, xb, N);

    // 6. layer-1 gemm (mode 0): xb -> hb, el, er
    gemm_mfma_kernel<<<(N + 127) / 128, 256, 0, stream>>>(
        xb, Whs, Wls, Mhs, Mls, hb, el, er, pred_W, yel, N, 0);

    // 7. middle aggregation (fabric-bound gather) -> xb
    agg_mid_kernel<<<(N + 15) / 16, 256, 0, stream>>>(
        hb, el, er, rowp, deg, col, conv_b + 128, xb, N);

    // 8. layer-2 gemm (mode 1): xb -> yel, er
    gemm_mfma_kernel<<<(N + 127) / 128, 256, 0, stream>>>(
        xb, Whs + 16384, Wls + 16384, Mhs + 2048, Mls + 2048,
        hb, el, er, pred_W, yel, N, 1);

    // 9. last aggregation -> logits
    agg2_kernel<<<(N + 15) / 16, 256, 0, stream>>>(
        yel, er, rowp, deg, col, prm, (float*)d_out, N);
}